// Round 3
// baseline (407.052 us; speedup 1.0000x reference)
//
#include <hip/hip_runtime.h>
#include <hip/hip_bf16.h>

#define LL 4096
#define FL 2049
#define DKN 128
#define DMOD 768

// ws layout (float units)
#define TW_OFF   0                          // 2048 float2
#define XT_OFF   4096                       // [2][2][128][4096] fp32 = 2097152 floats
#define SPEC_OFF (4096 + 2097152)           // [512][2049] float2 = 2098176 floats
#define Z_OFF    (SPEC_OFF + 2098176)       // [2][2][2049]
// xtb (bf16 [4][4096][128]) aliases the spec region (dead after irfft)
#define QKH_OFF  4207624                    // bf16-hi [q|k][2][4096][768] = 6291456 floats
#define QKL_OFF  (QKH_OFF + 6291456)        // bf16-lo
#define WH_OFF   (QKL_OFF + 6291456)        // bf16-hi [Wq|Wk][128][768] = 98304 floats
#define WL_OFF   (WH_OFF + 98304)

using bf16x8 = __attribute__((ext_vector_type(8))) short;
using f32x4  = __attribute__((ext_vector_type(4))) float;

__device__ __forceinline__ float2 cmul(float2 a, float2 b) {
    return make_float2(a.x * b.x - a.y * b.y, a.x * b.y + a.y * b.x);
}
__device__ __forceinline__ int SWZ(int a) { return a ^ ((a >> 4) & 15); }
__device__ __forceinline__ ushort f2bf(float f) {
    __hip_bfloat16 h = __float2bfloat16(f);
    return *(ushort*)&h;
}
__device__ __forceinline__ float bf2f(ushort u) {
    __hip_bfloat16 h = *(__hip_bfloat16*)&u;
    return __bfloat162float(h);
}

// ---------------- twiddle table ----------------
__global__ void k_twiddle(float2* __restrict__ tw) {
    int j = blockIdx.x * 256 + threadIdx.x;
    if (j < 2048) {
        double a = -2.0 * 3.14159265358979323846 * (double)j / 4096.0;
        tw[j] = make_float2((float)cos(a), (float)sin(a));
    }
}

// ---------------- fp32 -> bf16 hi/lo split ----------------
__global__ __launch_bounds__(256) void k_cvt(const float* __restrict__ src,
                                             ushort* __restrict__ hi,
                                             ushort* __restrict__ lo, int n) {
    int i8 = (blockIdx.x * 256 + threadIdx.x) * 8;
    if (i8 >= n) return;
    float4 a = *(const float4*)&src[i8];
    float4 b = *(const float4*)&src[i8 + 4];
    float v[8] = {a.x, a.y, a.z, a.w, b.x, b.y, b.z, b.w};
    union { ushort us[8]; uint4 q; } ph, pl;
#pragma unroll
    for (int u = 0; u < 8; u++) {
        ushort h = f2bf(v[u]);
        ph.us[u] = h;
        pl.us[u] = f2bf(v[u] - bf2f(h));
    }
    *(uint4*)&hi[i8] = ph.q;
    *(uint4*)&lo[i8] = pl.q;
}

// ---------------- projection GEMM (split-bf16 MFMA): xt[tz*2+b][d][l] = X . W^T + bias ----------------
__global__ __launch_bounds__(256) void k_proj(const ushort* __restrict__ XH,
                                              const ushort* __restrict__ XL,
                                              const ushort* __restrict__ WH,
                                              const ushort* __restrict__ WL,
                                              const float* __restrict__ bq,
                                              const float* __restrict__ bk,
                                              float* __restrict__ xt) {
    int tz = blockIdx.z, b = blockIdx.y;
    int l0 = blockIdx.x * 64;
    int t = threadIdx.x, w = t >> 6, lane = t & 63;
    int g = lane >> 4, c = lane & 15;
    size_t xrow0 = ((size_t)(tz * 2 + b)) * LL + l0;
    const ushort* WHt = WH + (size_t)tz * DKN * DMOD;
    const ushort* WLt = WL + (size_t)tz * DKN * DMOD;
    const float* bias = tz ? bk : bq;
    float* outp = xt + (size_t)(tz * 2 + b) * DKN * LL;
    f32x4 acc[2][4] = {};
    for (int ks = 0; ks < 24; ks++) {
        int kb = ks * 32 + g * 8;
        bf16x8 ah[2], al[2], xh[4], xl[4];
#pragma unroll
        for (int dt = 0; dt < 2; dt++) {
            size_t ro = (size_t)(w * 32 + dt * 16 + c) * DMOD + kb;
            ah[dt] = *(const bf16x8*)&WHt[ro];
            al[dt] = *(const bf16x8*)&WLt[ro];
        }
#pragma unroll
        for (int nt = 0; nt < 4; nt++) {
            size_t ro = (xrow0 + nt * 16 + c) * DMOD + kb;
            xh[nt] = *(const bf16x8*)&XH[ro];
            xl[nt] = *(const bf16x8*)&XL[ro];
        }
#pragma unroll
        for (int dt = 0; dt < 2; dt++)
#pragma unroll
            for (int nt = 0; nt < 4; nt++) {
                acc[dt][nt] = __builtin_amdgcn_mfma_f32_16x16x32_bf16(ah[dt], xh[nt], acc[dt][nt], 0, 0, 0);
                acc[dt][nt] = __builtin_amdgcn_mfma_f32_16x16x32_bf16(ah[dt], xl[nt], acc[dt][nt], 0, 0, 0);
                acc[dt][nt] = __builtin_amdgcn_mfma_f32_16x16x32_bf16(al[dt], xh[nt], acc[dt][nt], 0, 0, 0);
            }
    }
#pragma unroll
    for (int dt = 0; dt < 2; dt++)
#pragma unroll
        for (int r = 0; r < 4; r++) {
            int d = w * 32 + dt * 16 + g * 4 + r;
            float bd = bias[d];
#pragma unroll
            for (int nt = 0; nt < 4; nt++)
                outp[(size_t)d * LL + l0 + nt * 16 + c] = acc[dt][nt][r] + bd;
        }
}

// ---------------- radix-4 in-place Stockham FFT (N=4096), swizzled LDS ----------------
template <int INV>
__global__ __launch_bounds__(512) void k_fft4(const float* __restrict__ xin,
                                              float2* __restrict__ spec,
                                              const float* __restrict__ zsel,
                                              float* __restrict__ xout,
                                              const float2* __restrict__ tw) {
    __shared__ float2 buf[4096];
    int ser = blockIdx.x;   // (tensor*2+b)*128 + d
    int t   = threadIdx.x;
    if (!INV) {
        const float* x = xin + (size_t)ser * LL;
        for (int i = t; i < 4096; i += 512) buf[SWZ(i)] = make_float2(x[i], 0.f);
    } else {
        const float2* sp = spec + (size_t)ser * FL;
        const float*  zz = zsel + (size_t)(ser >> 7) * FL;
        for (int f = t; f < FL; f += 512) {
            float2 v = sp[f];
            float  m = zz[f];
            float2 vm = make_float2(v.x * m, v.y * m);
            buf[SWZ(f)] = vm;
            if (f > 0 && f < 2048) buf[SWZ(4096 - f)] = make_float2(vm.x, -vm.y);
        }
    }
    __syncthreads();
#pragma unroll
    for (int st = 0; st < 6; st++) {
        int Lm1 = (1 << (2 * st)) - 1;
        float2 x0[2], x1[2], x2[2], x3[2];
#pragma unroll
        for (int ii = 0; ii < 2; ii++) {
            int idx = t + 512 * ii;
            x0[ii] = buf[SWZ(idx)];
            x1[ii] = buf[SWZ(idx + 1024)];
            x2[ii] = buf[SWZ(idx + 2048)];
            x3[ii] = buf[SWZ(idx + 3072)];
        }
        __syncthreads();
#pragma unroll
        for (int ii = 0; ii < 2; ii++) {
            int idx = t + 512 * ii;
            int q = idx & Lm1;
            int r = idx - q;
            int wbase = q + (r << 2);
            int L = Lm1 + 1;
            float2 a0 = x0[ii], a1 = x1[ii], a2 = x2[ii], a3 = x3[ii];
            float2 t0 = make_float2(a0.x + a2.x, a0.y + a2.y);
            float2 t1 = make_float2(a0.x - a2.x, a0.y - a2.y);
            float2 t2 = make_float2(a1.x + a3.x, a1.y + a3.y);
            float2 t3 = make_float2(a1.x - a3.x, a1.y - a3.y);
            float2 y0 = make_float2(t0.x + t2.x, t0.y + t2.y);
            float2 y2 = make_float2(t0.x - t2.x, t0.y - t2.y);
            float2 y1, y3;
            if (!INV) {
                y1 = make_float2(t1.x + t3.y, t1.y - t3.x);
                y3 = make_float2(t1.x - t3.y, t1.y + t3.x);
            } else {
                y1 = make_float2(t1.x - t3.y, t1.y + t3.x);
                y3 = make_float2(t1.x + t3.y, t1.y - t3.x);
            }
            float2 w1 = tw[r];
            float2 w2 = tw[2 * r];
            if (INV) { w1.y = -w1.y; w2.y = -w2.y; }
            float2 w3 = cmul(w1, w2);
            buf[SWZ(wbase)]         = y0;
            buf[SWZ(wbase + L)]     = cmul(y1, w1);
            buf[SWZ(wbase + 2 * L)] = cmul(y2, w2);
            buf[SWZ(wbase + 3 * L)] = cmul(y3, w3);
        }
        __syncthreads();
    }
    if (!INV) {
        float2* sp = spec + (size_t)ser * FL;
        for (int f = t; f < FL; f += 512) sp[f] = buf[SWZ(f)];
    } else {
        float* xo = xout + (size_t)ser * LL;
        const float sc = 1.0f / 4096.0f;
        for (int i = t; i < 4096; i += 512) xo[i] = buf[SWZ(i)].x * sc;
    }
}

// ---------------- selector MLP: z[tensor][b][f] ----------------
__global__ __launch_bounds__(64) void k_selector(const float2* __restrict__ spec,
                                                 const float* __restrict__ W1,
                                                 const float* __restrict__ b1,
                                                 const float* __restrict__ W2,
                                                 const float* __restrict__ b2,
                                                 const float* __restrict__ noise,
                                                 float* __restrict__ z,
                                                 int tensor) {
    int f = blockIdx.x;
    int b = blockIdx.y;
    int j = threadIdx.x;
    __shared__ __align__(16) float xr[128];
    const float2* sp = spec + (size_t)(tensor * 2 + b) * DKN * FL;
    xr[j]      = sp[(size_t)j * FL + f].x;
    xr[j + 64] = sp[(size_t)(j + 64) * FL + f].x;
    __syncthreads();
    float acc = b1[j];
    const float4* w4 = (const float4*)&W1[(size_t)j * 128];
    const float4* x4 = (const float4*)xr;
#pragma unroll
    for (int d4 = 0; d4 < 32; d4++) {
        float4 w = w4[d4];
        float4 x = x4[d4];
        acc = fmaf(x.x, w.x, acc);
        acc = fmaf(x.y, w.y, acc);
        acc = fmaf(x.z, w.z, acc);
        acc = fmaf(x.w, w.w, acc);
    }
    float h = fmaxf(acc, 0.f);
    float l0 = h * W2[j];
    float l1 = h * W2[64 + j];
#pragma unroll
    for (int off = 32; off >= 1; off >>= 1) {
        l0 += __shfl_down(l0, off);
        l1 += __shfl_down(l1, off);
    }
    if (j == 0) {
        l0 += b2[0];
        l1 += b2[1];
        const float* nz = noise + ((size_t)b * FL + f) * 2;
        float g0 = -logf(-logf(nz[0] + 1e-9f) + 1e-9f);
        float g1 = -logf(-logf(nz[1] + 1e-9f) + 1e-9f);
        float a0 = l0 + g0, a1 = l1 + g1;
        z[(size_t)(tensor * 2 + b) * FL + f] = 1.f / (1.f + expf(a0 - a1));
    }
}

// ---------------- transpose fp32 [tb][d][l] -> bf16 [tb][l][d] ----------------
__global__ __launch_bounds__(256) void k_tr(const float* __restrict__ xt,
                                            ushort* __restrict__ xtb) {
    __shared__ float s[64][129];
    int tb = blockIdx.y;
    int l0 = blockIdx.x * 64;
    int t  = threadIdx.x;
    const float* gp = xt + (size_t)tb * DKN * LL;
    int d = t >> 1, c0 = (t & 1) * 32;
#pragma unroll
    for (int j4 = 0; j4 < 8; j4++) {
        float4 v = *(const float4*)&gp[(size_t)d * LL + l0 + c0 + j4 * 4];
        s[c0 + j4 * 4 + 0][d] = v.x;
        s[c0 + j4 * 4 + 1][d] = v.y;
        s[c0 + j4 * 4 + 2][d] = v.z;
        s[c0 + j4 * 4 + 3][d] = v.w;
    }
    __syncthreads();
    int l = t >> 2, dc0 = (t & 3) * 32;
    ushort* o = xtb + (size_t)tb * LL * DKN + (size_t)(l0 + l) * DKN + dc0;
#pragma unroll
    for (int c8 = 0; c8 < 4; c8++) {
        union { ushort us[8]; uint4 v; } pk;
#pragma unroll
        for (int u = 0; u < 8; u++) pk.us[u] = f2bf(s[l][dc0 + c8 * 8 + u]);
        *(uint4*)&o[c8 * 8] = pk.v;
    }
}

// ---------------- fused scores + masked softmax (flash 2-pass) ----------------
// block: 32 rows (2 ltiles x 16), 4 waves each owning a 1024-col quarter.
__global__ __launch_bounds__(256) void k_scores_soft(const ushort* __restrict__ xtb,
                                                     const int* __restrict__ mask,
                                                     float* __restrict__ out) {
    int b  = blockIdx.y;
    int l0 = blockIdx.x * 32;
    int t = threadIdx.x, w = t >> 6, lane = t & 63;
    int g = lane >> 4, c = lane & 15;
    const ushort* A = xtb + (size_t)b * LL * DKN;
    const ushort* B = xtb + (size_t)(2 + b) * LL * DKN;
    const int* mk = mask + (size_t)b * LL;
    const float sc = 0.08838834764831843f;  // 1/sqrt(128)
    bf16x8 af[2][4];
#pragma unroll
    for (int lt = 0; lt < 2; lt++)
#pragma unroll
        for (int kk = 0; kk < 4; kk++)
            af[lt][kk] = *(const bf16x8*)&A[(size_t)(l0 + lt * 16 + c) * DKN + kk * 32 + g * 8];
    float rM[2][4], rS[2][4];
#pragma unroll
    for (int lt = 0; lt < 2; lt++)
#pragma unroll
        for (int r = 0; r < 4; r++) { rM[lt][r] = -3.0e38f; rS[lt][r] = 0.f; }
    // ---- pass 1: online (max,sum) ----
    for (int mt = 0; mt < 16; mt++) {
        int m0 = w * 1024 + mt * 64;
        f32x4 acc[2][4] = {};
#pragma unroll
        for (int kk = 0; kk < 4; kk++) {
            bf16x8 bfr[4];
#pragma unroll
            for (int nt = 0; nt < 4; nt++)
                bfr[nt] = *(const bf16x8*)&B[(size_t)(m0 + nt * 16 + c) * DKN + kk * 32 + g * 8];
#pragma unroll
            for (int lt = 0; lt < 2; lt++)
#pragma unroll
                for (int nt = 0; nt < 4; nt++)
                    acc[lt][nt] = __builtin_amdgcn_mfma_f32_16x16x32_bf16(af[lt][kk], bfr[nt], acc[lt][nt], 0, 0, 0);
        }
        int mv[4];
#pragma unroll
        for (int nt = 0; nt < 4; nt++) mv[nt] = mk[m0 + nt * 16 + c];
#pragma unroll
        for (int lt = 0; lt < 2; lt++)
#pragma unroll
            for (int r = 0; r < 4; r++) {
                float sv[4];
                float vmax = -3.0e38f;
#pragma unroll
                for (int nt = 0; nt < 4; nt++) {
                    float s = mv[nt] ? acc[lt][nt][r] * sc : -1.0e9f;
                    sv[nt] = s;
                    vmax = fmaxf(vmax, s);
                }
                float nm = fmaxf(rM[lt][r], vmax);
                float ssum = 0.f;
#pragma unroll
                for (int nt = 0; nt < 4; nt++) ssum += __expf(sv[nt] - nm);
                rS[lt][r] = rS[lt][r] * __expf(rM[lt][r] - nm) + ssum;
                rM[lt][r] = nm;
            }
    }
    // ---- merge across the 16 col-lanes ----
#pragma unroll
    for (int lt = 0; lt < 2; lt++)
#pragma unroll
        for (int r = 0; r < 4; r++) {
            float M = rM[lt][r], S = rS[lt][r];
#pragma unroll
            for (int off = 1; off < 16; off <<= 1) {
                float om = __shfl_xor(M, off);
                float os = __shfl_xor(S, off);
                float nm = fmaxf(M, om);
                S = S * __expf(M - nm) + os * __expf(om - nm);
                M = nm;
            }
            rM[lt][r] = M; rS[lt][r] = S;
        }
    // ---- merge across 4 waves via LDS ----
    __shared__ float smM[4][32], smS[4][32];
    if (c == 0) {
#pragma unroll
        for (int lt = 0; lt < 2; lt++)
#pragma unroll
            for (int r = 0; r < 4; r++) {
                smM[w][lt * 16 + g * 4 + r] = rM[lt][r];
                smS[w][lt * 16 + g * 4 + r] = rS[lt][r];
            }
    }
    __syncthreads();
    float Mf[2][4], Iv[2][4];
#pragma unroll
    for (int lt = 0; lt < 2; lt++)
#pragma unroll
        for (int r = 0; r < 4; r++) {
            int row = lt * 16 + g * 4 + r;
            float M = -3.0e38f, S = 0.f;
#pragma unroll
            for (int ww = 0; ww < 4; ww++) {
                float om = smM[ww][row];
                float os = smS[ww][row];
                float nm = fmaxf(M, om);
                S = S * __expf(M - nm) + os * __expf(om - nm);
                M = nm;
            }
            Mf[lt][r] = M;
            Iv[lt][r] = 1.0f / S;
        }
    // ---- pass 2: recompute and write normalized ----
    for (int mt = 0; mt < 16; mt++) {
        int m0 = w * 1024 + mt * 64;
        f32x4 acc[2][4] = {};
#pragma unroll
        for (int kk = 0; kk < 4; kk++) {
            bf16x8 bfr[4];
#pragma unroll
            for (int nt = 0; nt < 4; nt++)
                bfr[nt] = *(const bf16x8*)&B[(size_t)(m0 + nt * 16 + c) * DKN + kk * 32 + g * 8];
#pragma unroll
            for (int lt = 0; lt < 2; lt++)
#pragma unroll
                for (int nt = 0; nt < 4; nt++)
                    acc[lt][nt] = __builtin_amdgcn_mfma_f32_16x16x32_bf16(af[lt][kk], bfr[nt], acc[lt][nt], 0, 0, 0);
        }
        int mv[4];
#pragma unroll
        for (int nt = 0; nt < 4; nt++) mv[nt] = mk[m0 + nt * 16 + c];
#pragma unroll
        for (int lt = 0; lt < 2; lt++)
#pragma unroll
            for (int r = 0; r < 4; r++) {
                int l = l0 + lt * 16 + g * 4 + r;
                float* orow = out + ((size_t)(b * LL + l)) * LL;
#pragma unroll
                for (int nt = 0; nt < 4; nt++) {
                    float s = mv[nt] ? acc[lt][nt][r] * sc : -1.0e9f;
                    orow[m0 + nt * 16 + c] = __expf(s - Mf[lt][r]) * Iv[lt][r];
                }
            }
    }
}

extern "C" void kernel_launch(void* const* d_in, const int* in_sizes, int n_in,
                              void* d_out, int out_size, void* d_ws, size_t ws_size,
                              hipStream_t stream) {
    (void)in_sizes; (void)n_in; (void)out_size; (void)ws_size;
    const float* query  = (const float*)d_in[0];
    const float* key    = (const float*)d_in[1];
    const int*   mask   = (const int*)d_in[2];
    const float* Wq     = (const float*)d_in[3];
    const float* bq     = (const float*)d_in[4];
    const float* Wk     = (const float*)d_in[5];
    const float* bk     = (const float*)d_in[6];
    const float* qW1    = (const float*)d_in[7];
    const float* qb1    = (const float*)d_in[8];
    const float* qW2    = (const float*)d_in[9];
    const float* qb2    = (const float*)d_in[10];
    const float* kW1    = (const float*)d_in[11];
    const float* kb1    = (const float*)d_in[12];
    const float* kW2    = (const float*)d_in[13];
    const float* kb2    = (const float*)d_in[14];
    const float* qnoise = (const float*)d_in[15];
    const float* knoise = (const float*)d_in[16];

    float*  ws   = (float*)d_ws;
    float2* tw   = (float2*)(ws + TW_OFF);
    float*  xt   = ws + XT_OFF;                 // [tensor][b][d][l] fp32
    float2* spec = (float2*)(ws + SPEC_OFF);    // [tensor*2+b][d][2049]
    ushort* xtb  = (ushort*)(ws + SPEC_OFF);    // bf16 [tb][l][d], aliases spec
    float*  zsel = ws + Z_OFF;
    ushort* qkh  = (ushort*)(ws + QKH_OFF);     // [q|k][2][4096][768] bf16 hi
    ushort* qkl  = (ushort*)(ws + QKL_OFF);
    ushort* wh   = (ushort*)(ws + WH_OFF);      // [Wq|Wk][128][768] bf16 hi
    ushort* wl   = (ushort*)(ws + WL_OFF);
    float*  out  = (float*)d_out;

    const int NQK = 2 * LL * DMOD;   // 6291456
    const int NW  = DKN * DMOD;      // 98304

    k_twiddle<<<dim3(8), dim3(256), 0, stream>>>(tw);
    k_cvt<<<dim3(NQK / 2048), dim3(256), 0, stream>>>(query, qkh, qkl, NQK);
    k_cvt<<<dim3(NQK / 2048), dim3(256), 0, stream>>>(key, qkh + NQK, qkl + NQK, NQK);
    k_cvt<<<dim3(NW / 2048), dim3(256), 0, stream>>>(Wq, wh, wl, NW);
    k_cvt<<<dim3(NW / 2048), dim3(256), 0, stream>>>(Wk, wh + NW, wl + NW, NW);
    k_proj<<<dim3(64, 2, 2), dim3(256), 0, stream>>>(qkh, qkl, wh, wl, bq, bk, xt);
    k_fft4<0><<<dim3(512), dim3(512), 0, stream>>>(xt, spec, nullptr, nullptr, tw);
    k_selector<<<dim3(FL, 2), dim3(64), 0, stream>>>(spec, qW1, qb1, qW2, qb2, qnoise, zsel, 0);
    k_selector<<<dim3(FL, 2), dim3(64), 0, stream>>>(spec, kW1, kb1, kW2, kb2, knoise, zsel, 1);
    k_fft4<1><<<dim3(512), dim3(512), 0, stream>>>(nullptr, spec, zsel, xt, tw);
    k_tr<<<dim3(64, 4), dim3(256), 0, stream>>>(xt, xtb);
    k_scores_soft<<<dim3(128, 2), dim3(256), 0, stream>>>(xtb, mask, out);
}

// Round 4
// 392.063 us; speedup vs baseline: 1.0382x; 1.0382x over previous
//
#include <hip/hip_runtime.h>
#include <hip/hip_bf16.h>

#define LL 4096
#define FL 2049
#define DKN 128
#define DMOD 768

// ws layout (float units)
#define TW_OFF   0                          // 2048 float2
#define XT_OFF   4096                       // [2][2][128][4096] fp32 = 2097152 floats
#define SPEC_OFF (4096 + 2097152)           // [512][2049] float2 = 2098176 floats
#define Z_OFF    (SPEC_OFF + 2098176)       // [2][2][2049]
// xtb (bf16 [4][4096][128]) aliases the spec region (dead after irfft)
#define QKH_OFF  4207624                    // bf16-hi [q|k][2][4096][768] = 6291456 floats
#define QKL_OFF  (QKH_OFF + 6291456)        // bf16-lo
#define WH_OFF   (QKL_OFF + 6291456)        // bf16-hi [Wq|Wk][128][768] = 98304 floats
#define WL_OFF   (WH_OFF + 98304)

using bf16x8 = __attribute__((ext_vector_type(8))) short;
using f32x4  = __attribute__((ext_vector_type(4))) float;

__device__ __forceinline__ float2 cmul(float2 a, float2 b) {
    return make_float2(a.x * b.x - a.y * b.y, a.x * b.y + a.y * b.x);
}
__device__ __forceinline__ int SWZ(int a) { return a ^ ((a >> 4) & 15); }
__device__ __forceinline__ ushort f2bf(float f) {
    __hip_bfloat16 h = __float2bfloat16(f);
    return *(ushort*)&h;
}
__device__ __forceinline__ float bf2f(ushort u) {
    __hip_bfloat16 h = *(__hip_bfloat16*)&u;
    return __bfloat162float(h);
}

// ---------------- twiddle table ----------------
__global__ void k_twiddle(float2* __restrict__ tw) {
    int j = blockIdx.x * 256 + threadIdx.x;
    if (j < 2048) {
        double a = -2.0 * 3.14159265358979323846 * (double)j / 4096.0;
        tw[j] = make_float2((float)cos(a), (float)sin(a));
    }
}

// ---------------- fp32 -> bf16 hi/lo split (two sources per launch) ----------------
__global__ __launch_bounds__(256) void k_cvt(const float* __restrict__ s0,
                                             const float* __restrict__ s1,
                                             ushort* __restrict__ hi,
                                             ushort* __restrict__ lo, int n) {
    const float* src = blockIdx.y ? s1 : s0;
    ushort* h = hi + (size_t)blockIdx.y * n;
    ushort* l = lo + (size_t)blockIdx.y * n;
    int i8 = (blockIdx.x * 256 + threadIdx.x) * 8;
    if (i8 >= n) return;
    float4 a = *(const float4*)&src[i8];
    float4 b = *(const float4*)&src[i8 + 4];
    float v[8] = {a.x, a.y, a.z, a.w, b.x, b.y, b.z, b.w};
    union { ushort us[8]; uint4 q; } ph, pl;
#pragma unroll
    for (int u = 0; u < 8; u++) {
        ushort hh = f2bf(v[u]);
        ph.us[u] = hh;
        pl.us[u] = f2bf(v[u] - bf2f(hh));
    }
    *(uint4*)&h[i8] = ph.q;
    *(uint4*)&l[i8] = pl.q;
}

// ---------------- projection GEMM (split-bf16 MFMA): xt[tz*2+b][d][l] = X . W^T + bias ----------------
__global__ __launch_bounds__(256) void k_proj(const ushort* __restrict__ XH,
                                              const ushort* __restrict__ XL,
                                              const ushort* __restrict__ WH,
                                              const ushort* __restrict__ WL,
                                              const float* __restrict__ bq,
                                              const float* __restrict__ bk,
                                              float* __restrict__ xt) {
    int tz = blockIdx.z, b = blockIdx.y;
    int l0 = blockIdx.x * 64;
    int t = threadIdx.x, w = t >> 6, lane = t & 63;
    int g = lane >> 4, c = lane & 15;
    size_t xrow0 = ((size_t)(tz * 2 + b)) * LL + l0;
    const ushort* WHt = WH + (size_t)tz * DKN * DMOD;
    const ushort* WLt = WL + (size_t)tz * DKN * DMOD;
    const float* bias = tz ? bk : bq;
    float* outp = xt + (size_t)(tz * 2 + b) * DKN * LL;
    f32x4 acc[2][4] = {};
    for (int ks = 0; ks < 24; ks++) {
        int kb = ks * 32 + g * 8;
        bf16x8 ah[2], al[2], xh[4], xl[4];
#pragma unroll
        for (int dt = 0; dt < 2; dt++) {
            size_t ro = (size_t)(w * 32 + dt * 16 + c) * DMOD + kb;
            ah[dt] = *(const bf16x8*)&WHt[ro];
            al[dt] = *(const bf16x8*)&WLt[ro];
        }
#pragma unroll
        for (int nt = 0; nt < 4; nt++) {
            size_t ro = (xrow0 + nt * 16 + c) * DMOD + kb;
            xh[nt] = *(const bf16x8*)&XH[ro];
            xl[nt] = *(const bf16x8*)&XL[ro];
        }
#pragma unroll
        for (int dt = 0; dt < 2; dt++)
#pragma unroll
            for (int nt = 0; nt < 4; nt++) {
                acc[dt][nt] = __builtin_amdgcn_mfma_f32_16x16x32_bf16(ah[dt], xh[nt], acc[dt][nt], 0, 0, 0);
                acc[dt][nt] = __builtin_amdgcn_mfma_f32_16x16x32_bf16(ah[dt], xl[nt], acc[dt][nt], 0, 0, 0);
                acc[dt][nt] = __builtin_amdgcn_mfma_f32_16x16x32_bf16(al[dt], xh[nt], acc[dt][nt], 0, 0, 0);
            }
    }
#pragma unroll
    for (int dt = 0; dt < 2; dt++)
#pragma unroll
        for (int r = 0; r < 4; r++) {
            int d = w * 32 + dt * 16 + g * 4 + r;
            float bd = bias[d];
#pragma unroll
            for (int nt = 0; nt < 4; nt++)
                outp[(size_t)d * LL + l0 + nt * 16 + c] = acc[dt][nt][r] + bd;
        }
}

// ---------------- radix-4 in-place Stockham FFT (N=4096), swizzled LDS, LDS twiddles ----------------
template <int INV>
__global__ __launch_bounds__(512) void k_fft4(const float* __restrict__ xin,
                                              float2* __restrict__ spec,
                                              const float* __restrict__ zsel,
                                              float* __restrict__ xout,
                                              const float2* __restrict__ tw) {
    __shared__ float2 buf[4096];
    __shared__ float2 ltw[2048];
    int ser = blockIdx.x;   // (tensor*2+b)*128 + d
    int t   = threadIdx.x;
    for (int i = t; i < 2048; i += 512) ltw[i] = tw[i];
    if (!INV) {
        const float* x = xin + (size_t)ser * LL;
        for (int i = t; i < 4096; i += 512) buf[SWZ(i)] = make_float2(x[i], 0.f);
    } else {
        const float2* sp = spec + (size_t)ser * FL;
        const float*  zz = zsel + (size_t)(ser >> 7) * FL;
        for (int f = t; f < FL; f += 512) {
            float2 v = sp[f];
            float  m = zz[f];
            float2 vm = make_float2(v.x * m, v.y * m);
            buf[SWZ(f)] = vm;
            if (f > 0 && f < 2048) buf[SWZ(4096 - f)] = make_float2(vm.x, -vm.y);
        }
    }
    __syncthreads();
#pragma unroll
    for (int st = 0; st < 6; st++) {
        int Lm1 = (1 << (2 * st)) - 1;
        float2 x0[2], x1[2], x2[2], x3[2];
#pragma unroll
        for (int ii = 0; ii < 2; ii++) {
            int idx = t + 512 * ii;
            x0[ii] = buf[SWZ(idx)];
            x1[ii] = buf[SWZ(idx + 1024)];
            x2[ii] = buf[SWZ(idx + 2048)];
            x3[ii] = buf[SWZ(idx + 3072)];
        }
        __syncthreads();
#pragma unroll
        for (int ii = 0; ii < 2; ii++) {
            int idx = t + 512 * ii;
            int q = idx & Lm1;
            int r = idx - q;
            int wbase = q + (r << 2);
            int L = Lm1 + 1;
            float2 a0 = x0[ii], a1 = x1[ii], a2 = x2[ii], a3 = x3[ii];
            float2 t0 = make_float2(a0.x + a2.x, a0.y + a2.y);
            float2 t1 = make_float2(a0.x - a2.x, a0.y - a2.y);
            float2 t2 = make_float2(a1.x + a3.x, a1.y + a3.y);
            float2 t3 = make_float2(a1.x - a3.x, a1.y - a3.y);
            float2 y0 = make_float2(t0.x + t2.x, t0.y + t2.y);
            float2 y2 = make_float2(t0.x - t2.x, t0.y - t2.y);
            float2 y1, y3;
            if (!INV) {
                y1 = make_float2(t1.x + t3.y, t1.y - t3.x);
                y3 = make_float2(t1.x - t3.y, t1.y + t3.x);
            } else {
                y1 = make_float2(t1.x - t3.y, t1.y + t3.x);
                y3 = make_float2(t1.x + t3.y, t1.y - t3.x);
            }
            float2 w1 = ltw[r];
            float2 w2 = ltw[2 * r];
            if (INV) { w1.y = -w1.y; w2.y = -w2.y; }
            float2 w3 = cmul(w1, w2);
            buf[SWZ(wbase)]         = y0;
            buf[SWZ(wbase + L)]     = cmul(y1, w1);
            buf[SWZ(wbase + 2 * L)] = cmul(y2, w2);
            buf[SWZ(wbase + 3 * L)] = cmul(y3, w3);
        }
        __syncthreads();
    }
    if (!INV) {
        float2* sp = spec + (size_t)ser * FL;
        for (int f = t; f < FL; f += 512) sp[f] = buf[SWZ(f)];
    } else {
        float* xo = xout + (size_t)ser * LL;
        const float sc = 1.0f / 4096.0f;
        for (int i = t; i < 4096; i += 512) xo[i] = buf[SWZ(i)].x * sc;
    }
}

// ---------------- selector MLP, tiled: 64 freqs/block, 4 waves x 16 f, lane = hidden j ----------------
__global__ __launch_bounds__(256) void k_sel2(const float2* __restrict__ spec,
                                              const float* __restrict__ qW1,
                                              const float* __restrict__ qb1,
                                              const float* __restrict__ qW2,
                                              const float* __restrict__ qb2,
                                              const float* __restrict__ kW1,
                                              const float* __restrict__ kb1,
                                              const float* __restrict__ kW2,
                                              const float* __restrict__ kb2,
                                              const float* __restrict__ qnoise,
                                              const float* __restrict__ knoise,
                                              float* __restrict__ z) {
    int tz = blockIdx.z, b = blockIdx.y;
    int f0 = blockIdx.x * 64;
    const float* W1 = tz ? kW1 : qW1;
    const float* b1 = tz ? kb1 : qb1;
    const float* W2 = tz ? kW2 : qW2;
    const float* b2 = tz ? kb2 : qb2;
    const float* nz = tz ? knoise : qnoise;
    __shared__ float xr[64][132];
    const float2* sp = spec + (size_t)(tz * 2 + b) * DKN * FL;
    int t = threadIdx.x;
    {
        int d = t >> 1, half = t & 1;
        const float2* row = sp + (size_t)d * FL;
#pragma unroll
        for (int i2 = 0; i2 < 32; i2++) {
            int fi = f0 + half * 32 + i2;
            float v = (fi < FL) ? row[fi].x : 0.f;
            xr[half * 32 + i2][d] = v;
        }
    }
    __syncthreads();
    int lane = t & 63, fg = t >> 6;
    float acc[16];
    float bj = b1[lane];
#pragma unroll
    for (int ff = 0; ff < 16; ff++) acc[ff] = bj;
    const float4* w1r = (const float4*)&W1[(size_t)lane * 128];
    for (int d4 = 0; d4 < 32; d4++) {
        float4 wv = w1r[d4];
#pragma unroll
        for (int ff = 0; ff < 16; ff++) {
            float4 xv = *(const float4*)&xr[fg * 16 + ff][d4 * 4];
            acc[ff] = fmaf(xv.x, wv.x, acc[ff]);
            acc[ff] = fmaf(xv.y, wv.y, acc[ff]);
            acc[ff] = fmaf(xv.z, wv.z, acc[ff]);
            acc[ff] = fmaf(xv.w, wv.w, acc[ff]);
        }
    }
    float w2a = W2[lane], w2b = W2[64 + lane];
    float l0f = 0.f, l1f = 0.f;
#pragma unroll
    for (int ff = 0; ff < 16; ff++) {
        float h = fmaxf(acc[ff], 0.f);
        float l0 = h * w2a, l1 = h * w2b;
#pragma unroll
        for (int off = 32; off >= 1; off >>= 1) {
            l0 += __shfl_xor(l0, off);
            l1 += __shfl_xor(l1, off);
        }
        if (lane == ff) { l0f = l0; l1f = l1; }
    }
    if (lane < 16) {
        int f = f0 + fg * 16 + lane;
        if (f < FL) {
            float a0 = l0f + b2[0];
            float a1 = l1f + b2[1];
            const float* np = nz + ((size_t)b * FL + f) * 2;
            float g0 = -logf(-logf(np[0] + 1e-9f) + 1e-9f);
            float g1 = -logf(-logf(np[1] + 1e-9f) + 1e-9f);
            a0 += g0; a1 += g1;
            z[(size_t)(tz * 2 + b) * FL + f] = 1.f / (1.f + expf(a0 - a1));
        }
    }
}

// ---------------- transpose fp32 [tb][d][l] -> bf16 [tb][l][d] ----------------
__global__ __launch_bounds__(256) void k_tr(const float* __restrict__ xt,
                                            ushort* __restrict__ xtb) {
    __shared__ float s[64][129];
    int tb = blockIdx.y;
    int l0 = blockIdx.x * 64;
    int t  = threadIdx.x;
    const float* gp = xt + (size_t)tb * DKN * LL;
    int d = t >> 1, c0 = (t & 1) * 32;
#pragma unroll
    for (int j4 = 0; j4 < 8; j4++) {
        float4 v = *(const float4*)&gp[(size_t)d * LL + l0 + c0 + j4 * 4];
        s[c0 + j4 * 4 + 0][d] = v.x;
        s[c0 + j4 * 4 + 1][d] = v.y;
        s[c0 + j4 * 4 + 2][d] = v.z;
        s[c0 + j4 * 4 + 3][d] = v.w;
    }
    __syncthreads();
    int l = t >> 2, dc0 = (t & 3) * 32;
    ushort* o = xtb + (size_t)tb * LL * DKN + (size_t)(l0 + l) * DKN + dc0;
#pragma unroll
    for (int c8 = 0; c8 < 4; c8++) {
        union { ushort us[8]; uint4 v; } pk;
#pragma unroll
        for (int u = 0; u < 8; u++) pk.us[u] = f2bf(s[l][dc0 + c8 * 8 + u]);
        *(uint4*)&o[c8 * 8] = pk.v;
    }
}

// ---------------- fused scores + masked softmax (flash 2-pass) ----------------
// block: 1024 threads = 16 waves; 32 rows/block; wave w owns cols [w*256, w*256+256)
__global__ __launch_bounds__(1024) void k_scores_soft(const ushort* __restrict__ xtb,
                                                      const int* __restrict__ mask,
                                                      float* __restrict__ out) {
    int b  = blockIdx.y;
    int l0 = blockIdx.x * 32;
    int t = threadIdx.x, w = t >> 6, lane = t & 63;
    int g = lane >> 4, c = lane & 15;
    const ushort* A = xtb + (size_t)b * LL * DKN;
    const ushort* B = xtb + (size_t)(2 + b) * LL * DKN;
    const int* mk = mask + (size_t)b * LL;
    const float sc = 0.08838834764831843f;  // 1/sqrt(128)
    bf16x8 af[2][4];
#pragma unroll
    for (int lt = 0; lt < 2; lt++)
#pragma unroll
        for (int kk = 0; kk < 4; kk++)
            af[lt][kk] = *(const bf16x8*)&A[(size_t)(l0 + lt * 16 + c) * DKN + kk * 32 + g * 8];
    float rM[2][4], rS[2][4];
#pragma unroll
    for (int lt = 0; lt < 2; lt++)
#pragma unroll
        for (int r = 0; r < 4; r++) { rM[lt][r] = -3.0e38f; rS[lt][r] = 0.f; }
    // ---- pass 1: online (max,sum) over this wave's 256 cols ----
    for (int mt = 0; mt < 4; mt++) {
        int m0 = w * 256 + mt * 64;
        f32x4 acc[2][4] = {};
#pragma unroll
        for (int kk = 0; kk < 4; kk++) {
            bf16x8 bfr[4];
#pragma unroll
            for (int nt = 0; nt < 4; nt++)
                bfr[nt] = *(const bf16x8*)&B[(size_t)(m0 + nt * 16 + c) * DKN + kk * 32 + g * 8];
#pragma unroll
            for (int lt = 0; lt < 2; lt++)
#pragma unroll
                for (int nt = 0; nt < 4; nt++)
                    acc[lt][nt] = __builtin_amdgcn_mfma_f32_16x16x32_bf16(af[lt][kk], bfr[nt], acc[lt][nt], 0, 0, 0);
        }
        int mv[4];
#pragma unroll
        for (int nt = 0; nt < 4; nt++) mv[nt] = mk[m0 + nt * 16 + c];
#pragma unroll
        for (int lt = 0; lt < 2; lt++)
#pragma unroll
            for (int r = 0; r < 4; r++) {
                float sv[4];
                float vmax = -3.0e38f;
#pragma unroll
                for (int nt = 0; nt < 4; nt++) {
                    float s = mv[nt] ? acc[lt][nt][r] * sc : -1.0e9f;
                    sv[nt] = s;
                    vmax = fmaxf(vmax, s);
                }
                float nm = fmaxf(rM[lt][r], vmax);
                float ssum = 0.f;
#pragma unroll
                for (int nt = 0; nt < 4; nt++) ssum += __expf(sv[nt] - nm);
                rS[lt][r] = rS[lt][r] * __expf(rM[lt][r] - nm) + ssum;
                rM[lt][r] = nm;
            }
    }
    // ---- merge across the 16 col-lanes (same g group) ----
#pragma unroll
    for (int lt = 0; lt < 2; lt++)
#pragma unroll
        for (int r = 0; r < 4; r++) {
            float M = rM[lt][r], S = rS[lt][r];
#pragma unroll
            for (int off = 1; off < 16; off <<= 1) {
                float om = __shfl_xor(M, off);
                float os = __shfl_xor(S, off);
                float nm = fmaxf(M, om);
                S = S * __expf(M - nm) + os * __expf(om - nm);
                M = nm;
            }
            rM[lt][r] = M; rS[lt][r] = S;
        }
    // ---- merge across 16 waves via LDS ----
    __shared__ float smM[16][32], smS[16][32];
    if (c == 0) {
#pragma unroll
        for (int lt = 0; lt < 2; lt++)
#pragma unroll
            for (int r = 0; r < 4; r++) {
                smM[w][lt * 16 + g * 4 + r] = rM[lt][r];
                smS[w][lt * 16 + g * 4 + r] = rS[lt][r];
            }
    }
    __syncthreads();
    float Mf[2][4], Iv[2][4];
#pragma unroll
    for (int lt = 0; lt < 2; lt++)
#pragma unroll
        for (int r = 0; r < 4; r++) {
            int row = lt * 16 + g * 4 + r;
            float M = -3.0e38f, S = 0.f;
#pragma unroll
            for (int ww = 0; ww < 16; ww++) {
                float om = smM[ww][row];
                float os = smS[ww][row];
                float nm = fmaxf(M, om);
                S = S * __expf(M - nm) + os * __expf(om - nm);
                M = nm;
            }
            Mf[lt][r] = M;
            Iv[lt][r] = 1.0f / S;
        }
    // ---- pass 2: recompute and write normalized ----
    for (int mt = 0; mt < 4; mt++) {
        int m0 = w * 256 + mt * 64;
        f32x4 acc[2][4] = {};
#pragma unroll
        for (int kk = 0; kk < 4; kk++) {
            bf16x8 bfr[4];
#pragma unroll
            for (int nt = 0; nt < 4; nt++)
                bfr[nt] = *(const bf16x8*)&B[(size_t)(m0 + nt * 16 + c) * DKN + kk * 32 + g * 8];
#pragma unroll
            for (int lt = 0; lt < 2; lt++)
#pragma unroll
                for (int nt = 0; nt < 4; nt++)
                    acc[lt][nt] = __builtin_amdgcn_mfma_f32_16x16x32_bf16(af[lt][kk], bfr[nt], acc[lt][nt], 0, 0, 0);
        }
        int mv[4];
#pragma unroll
        for (int nt = 0; nt < 4; nt++) mv[nt] = mk[m0 + nt * 16 + c];
#pragma unroll
        for (int lt = 0; lt < 2; lt++)
#pragma unroll
            for (int r = 0; r < 4; r++) {
                int l = l0 + lt * 16 + g * 4 + r;
                float* orow = out + ((size_t)(b * LL + l)) * LL;
#pragma unroll
                for (int nt = 0; nt < 4; nt++) {
                    float s = mv[nt] ? acc[lt][nt][r] * sc : -1.0e9f;
                    orow[m0 + nt * 16 + c] = __expf(s - Mf[lt][r]) * Iv[lt][r];
                }
            }
    }
}

extern "C" void kernel_launch(void* const* d_in, const int* in_sizes, int n_in,
                              void* d_out, int out_size, void* d_ws, size_t ws_size,
                              hipStream_t stream) {
    (void)in_sizes; (void)n_in; (void)out_size; (void)ws_size;
    const float* query  = (const float*)d_in[0];
    const float* key    = (const float*)d_in[1];
    const int*   mask   = (const int*)d_in[2];
    const float* Wq     = (const float*)d_in[3];
    const float* bq     = (const float*)d_in[4];
    const float* Wk     = (const float*)d_in[5];
    const float* bk     = (const float*)d_in[6];
    const float* qW1    = (const float*)d_in[7];
    const float* qb1    = (const float*)d_in[8];
    const float* qW2    = (const float*)d_in[9];
    const float* qb2    = (const float*)d_in[10];
    const float* kW1    = (const float*)d_in[11];
    const float* kb1    = (const float*)d_in[12];
    const float* kW2    = (const float*)d_in[13];
    const float* kb2    = (const float*)d_in[14];
    const float* qnoise = (const float*)d_in[15];
    const float* knoise = (const float*)d_in[16];

    float*  ws   = (float*)d_ws;
    float2* tw   = (float2*)(ws + TW_OFF);
    float*  xt   = ws + XT_OFF;                 // [tensor][b][d][l] fp32
    float2* spec = (float2*)(ws + SPEC_OFF);    // [tensor*2+b][d][2049]
    ushort* xtb  = (ushort*)(ws + SPEC_OFF);    // bf16 [tb][l][d], aliases spec
    float*  zsel = ws + Z_OFF;
    ushort* qkh  = (ushort*)(ws + QKH_OFF);     // [q|k][2][4096][768] bf16 hi
    ushort* qkl  = (ushort*)(ws + QKL_OFF);
    ushort* wh   = (ushort*)(ws + WH_OFF);      // [Wq|Wk][128][768] bf16 hi
    ushort* wl   = (ushort*)(ws + WL_OFF);
    float*  out  = (float*)d_out;

    const int NQK = 2 * LL * DMOD;   // 6291456
    const int NW  = DKN * DMOD;      // 98304

    k_twiddle<<<dim3(8), dim3(256), 0, stream>>>(tw);
    k_cvt<<<dim3(NQK / 2048, 2), dim3(256), 0, stream>>>(query, key, qkh, qkl, NQK);
    k_cvt<<<dim3(NW / 2048, 2), dim3(256), 0, stream>>>(Wq, Wk, wh, wl, NW);
    k_proj<<<dim3(64, 2, 2), dim3(256), 0, stream>>>(qkh, qkl, wh, wl, bq, bk, xt);
    k_fft4<0><<<dim3(512), dim3(512), 0, stream>>>(xt, spec, nullptr, nullptr, tw);
    k_sel2<<<dim3(33, 2, 2), dim3(256), 0, stream>>>(spec, qW1, qb1, qW2, qb2,
                                                     kW1, kb1, kW2, kb2, qnoise, knoise, zsel);
    k_fft4<1><<<dim3(512), dim3(512), 0, stream>>>(nullptr, spec, zsel, xt, tw);
    k_tr<<<dim3(64, 4), dim3(256), 0, stream>>>(xt, xtb);
    k_scores_soft<<<dim3(128, 2), dim3(1024), 0, stream>>>(xtb, mask, out);
}

// Round 7
// 357.467 us; speedup vs baseline: 1.1387x; 1.0968x over previous
//
#include <hip/hip_runtime.h>
#include <hip/hip_bf16.h>

#define LL 4096
#define FL 2049
#define DKN 128
#define DMOD 768

// ws layout (float units)
#define TW_OFF   0                          // 2048 float2
#define XT_OFF   4096                       // [2][2][128][4096] fp32 = 2097152 floats
#define SPEC_OFF (4096 + 2097152)           // [512][2049] float2 = 2098176 floats
#define Z_OFF    (SPEC_OFF + 2098176)       // [2][2][2049]
// xtb (bf16 [4][4096][128]) aliases the spec region (dead after irfft)
#define QKH_OFF  4207624                    // bf16 [q|k][2][4096][768] = 12582912 halves = 6291456 floats
#define WH_OFF   (QKH_OFF + 6291456)        // bf16 [Wq|Wk][128][768]  (FIX: was +3145728, overlapped key!)

using bf16x8 = __attribute__((ext_vector_type(8))) short;
using f32x4  = __attribute__((ext_vector_type(4))) float;

__device__ __forceinline__ float2 cmul(float2 a, float2 b) {
    return make_float2(a.x * b.x - a.y * b.y, a.x * b.y + a.y * b.x);
}
__device__ __forceinline__ int SWZ(int a) { return a ^ ((a >> 4) & 15); }
__device__ __forceinline__ ushort f2bf(float f) {
    __hip_bfloat16 h = __float2bfloat16(f);
    return *(ushort*)&h;
}
__device__ __forceinline__ float bfbits(unsigned u) {
    union { unsigned i; float f; } x; x.i = u; return x.f;
}

// ---------------- twiddle table ----------------
__global__ void k_twiddle(float2* __restrict__ tw) {
    int j = blockIdx.x * 256 + threadIdx.x;
    if (j < 2048) {
        double a = -2.0 * 3.14159265358979323846 * (double)j / 4096.0;
        tw[j] = make_float2((float)cos(a), (float)sin(a));
    }
}

// ---------------- fp32 -> bf16 (two sources per launch) ----------------
__global__ __launch_bounds__(256) void k_cvt(const float* __restrict__ s0,
                                             const float* __restrict__ s1,
                                             ushort* __restrict__ hi, int n) {
    const float* src = blockIdx.y ? s1 : s0;
    ushort* h = hi + (size_t)blockIdx.y * n;
    int i8 = (blockIdx.x * 256 + threadIdx.x) * 8;
    if (i8 >= n) return;
    float4 a = *(const float4*)&src[i8];
    float4 b = *(const float4*)&src[i8 + 4];
    float v[8] = {a.x, a.y, a.z, a.w, b.x, b.y, b.z, b.w};
    union { ushort us[8]; uint4 q; } ph;
#pragma unroll
    for (int u = 0; u < 8; u++) ph.us[u] = f2bf(v[u]);
    *(uint4*)&h[i8] = ph.q;
}

// ---------------- projection GEMM (bf16 MFMA): xt[tz*2+b][d][l] = X . W^T + bias ----------------
__global__ __launch_bounds__(256) void k_proj(const ushort* __restrict__ XH,
                                              const ushort* __restrict__ WH,
                                              const float* __restrict__ bq,
                                              const float* __restrict__ bk,
                                              float* __restrict__ xt) {
    int tz = blockIdx.z, b = blockIdx.y;
    int l0 = blockIdx.x * 64;
    int t = threadIdx.x, w = t >> 6, lane = t & 63;
    int g = lane >> 4, c = lane & 15;
    size_t xrow0 = ((size_t)(tz * 2 + b)) * LL + l0;
    const ushort* WHt = WH + (size_t)tz * DKN * DMOD;
    const float* bias = tz ? bk : bq;
    float* outp = xt + (size_t)(tz * 2 + b) * DKN * LL;
    f32x4 acc[2][4] = {};
    for (int ks = 0; ks < 24; ks++) {
        int kb = ks * 32 + g * 8;
        bf16x8 ah[2], xh[4];
#pragma unroll
        for (int dt = 0; dt < 2; dt++)
            ah[dt] = *(const bf16x8*)&WHt[(size_t)(w * 32 + dt * 16 + c) * DMOD + kb];
#pragma unroll
        for (int nt = 0; nt < 4; nt++)
            xh[nt] = *(const bf16x8*)&XH[(xrow0 + nt * 16 + c) * DMOD + kb];
#pragma unroll
        for (int dt = 0; dt < 2; dt++)
#pragma unroll
            for (int nt = 0; nt < 4; nt++)
                acc[dt][nt] = __builtin_amdgcn_mfma_f32_16x16x32_bf16(ah[dt], xh[nt], acc[dt][nt], 0, 0, 0);
    }
#pragma unroll
    for (int dt = 0; dt < 2; dt++)
#pragma unroll
        for (int r = 0; r < 4; r++) {
            int d = w * 32 + dt * 16 + g * 4 + r;
            float bd = bias[d];
#pragma unroll
            for (int nt = 0; nt < 4; nt++)
                outp[(size_t)d * LL + l0 + nt * 16 + c] = acc[dt][nt][r] + bd;
        }
}

// ---------------- radix-4 in-place Stockham FFT (N=4096), swizzled LDS, LDS twiddles ----------------
template <int INV>
__global__ __launch_bounds__(512) void k_fft4(const float* __restrict__ xin,
                                              float2* __restrict__ spec,
                                              const float* __restrict__ zsel,
                                              float* __restrict__ xout,
                                              const float2* __restrict__ tw) {
    __shared__ float2 buf[4096];
    __shared__ float2 ltw[2048];
    int ser = blockIdx.x;   // (tensor*2+b)*128 + d
    int t   = threadIdx.x;
    for (int i = t; i < 2048; i += 512) ltw[i] = tw[i];
    if (!INV) {
        const float* x = xin + (size_t)ser * LL;
        for (int i = t; i < 4096; i += 512) buf[SWZ(i)] = make_float2(x[i], 0.f);
    } else {
        const float2* sp = spec + (size_t)ser * FL;
        const float*  zz = zsel + (size_t)(ser >> 7) * FL;
        for (int f = t; f < FL; f += 512) {
            float2 v = sp[f];
            float  m = zz[f];
            float2 vm = make_float2(v.x * m, v.y * m);
            buf[SWZ(f)] = vm;
            if (f > 0 && f < 2048) buf[SWZ(4096 - f)] = make_float2(vm.x, -vm.y);
        }
    }
    __syncthreads();
#pragma unroll
    for (int st = 0; st < 6; st++) {
        int Lm1 = (1 << (2 * st)) - 1;
        float2 x0[2], x1[2], x2[2], x3[2];
#pragma unroll
        for (int ii = 0; ii < 2; ii++) {
            int idx = t + 512 * ii;
            x0[ii] = buf[SWZ(idx)];
            x1[ii] = buf[SWZ(idx + 1024)];
            x2[ii] = buf[SWZ(idx + 2048)];
            x3[ii] = buf[SWZ(idx + 3072)];
        }
        __syncthreads();
#pragma unroll
        for (int ii = 0; ii < 2; ii++) {
            int idx = t + 512 * ii;
            int q = idx & Lm1;
            int r = idx - q;
            int wbase = q + (r << 2);
            int L = Lm1 + 1;
            float2 a0 = x0[ii], a1 = x1[ii], a2 = x2[ii], a3 = x3[ii];
            float2 t0 = make_float2(a0.x + a2.x, a0.y + a2.y);
            float2 t1 = make_float2(a0.x - a2.x, a0.y - a2.y);
            float2 t2 = make_float2(a1.x + a3.x, a1.y + a3.y);
            float2 t3 = make_float2(a1.x - a3.x, a1.y - a3.y);
            float2 y0 = make_float2(t0.x + t2.x, t0.y + t2.y);
            float2 y2 = make_float2(t0.x - t2.x, t0.y - t2.y);
            float2 y1, y3;
            if (!INV) {
                y1 = make_float2(t1.x + t3.y, t1.y - t3.x);
                y3 = make_float2(t1.x - t3.y, t1.y + t3.x);
            } else {
                y1 = make_float2(t1.x - t3.y, t1.y + t3.x);
                y3 = make_float2(t1.x + t3.y, t1.y - t3.x);
            }
            float2 w1 = ltw[r];
            float2 w2 = ltw[2 * r];
            if (INV) { w1.y = -w1.y; w2.y = -w2.y; }
            float2 w3 = cmul(w1, w2);
            buf[SWZ(wbase)]         = y0;
            buf[SWZ(wbase + L)]     = cmul(y1, w1);
            buf[SWZ(wbase + 2 * L)] = cmul(y2, w2);
            buf[SWZ(wbase + 3 * L)] = cmul(y3, w3);
        }
        __syncthreads();
    }
    if (!INV) {
        float2* sp = spec + (size_t)ser * FL;
        for (int f = t; f < FL; f += 512) sp[f] = buf[SWZ(f)];
    } else {
        float* xo = xout + (size_t)ser * LL;
        const float sc = 1.0f / 4096.0f;
        for (int i = t; i < 4096; i += 512) xo[i] = buf[SWZ(i)].x * sc;
    }
}

// ---------------- selector MLP, tiled: 64 freqs/block, 4 waves x 16 f, lane = hidden j ----------------
__global__ __launch_bounds__(256) void k_sel2(const float2* __restrict__ spec,
                                              const float* __restrict__ qW1,
                                              const float* __restrict__ qb1,
                                              const float* __restrict__ qW2,
                                              const float* __restrict__ qb2,
                                              const float* __restrict__ kW1,
                                              const float* __restrict__ kb1,
                                              const float* __restrict__ kW2,
                                              const float* __restrict__ kb2,
                                              const float* __restrict__ qnoise,
                                              const float* __restrict__ knoise,
                                              float* __restrict__ z) {
    int tz = blockIdx.z, b = blockIdx.y;
    int f0 = blockIdx.x * 64;
    const float* W1 = tz ? kW1 : qW1;
    const float* b1 = tz ? kb1 : qb1;
    const float* W2 = tz ? kW2 : qW2;
    const float* b2 = tz ? kb2 : qb2;
    const float* nz = tz ? knoise : qnoise;
    __shared__ float xr[64][132];
    const float2* sp = spec + (size_t)(tz * 2 + b) * DKN * FL;
    int t = threadIdx.x;
    {
        int d = t >> 1, half = t & 1;
        const float2* row = sp + (size_t)d * FL;
#pragma unroll
        for (int i2 = 0; i2 < 32; i2++) {
            int fi = f0 + half * 32 + i2;
            float v = (fi < FL) ? row[fi].x : 0.f;
            xr[half * 32 + i2][d] = v;
        }
    }
    __syncthreads();
    int lane = t & 63, fg = t >> 6;
    float acc[16];
    float bj = b1[lane];
#pragma unroll
    for (int ff = 0; ff < 16; ff++) acc[ff] = bj;
    const float4* w1r = (const float4*)&W1[(size_t)lane * 128];
    for (int d4 = 0; d4 < 32; d4++) {
        float4 wv = w1r[d4];
#pragma unroll
        for (int ff = 0; ff < 16; ff++) {
            float4 xv = *(const float4*)&xr[fg * 16 + ff][d4 * 4];
            acc[ff] = fmaf(xv.x, wv.x, acc[ff]);
            acc[ff] = fmaf(xv.y, wv.y, acc[ff]);
            acc[ff] = fmaf(xv.z, wv.z, acc[ff]);
            acc[ff] = fmaf(xv.w, wv.w, acc[ff]);
        }
    }
    float w2a = W2[lane], w2b = W2[64 + lane];
    float l0f = 0.f, l1f = 0.f;
#pragma unroll
    for (int ff = 0; ff < 16; ff++) {
        float h = fmaxf(acc[ff], 0.f);
        float l0 = h * w2a, l1 = h * w2b;
#pragma unroll
        for (int off = 32; off >= 1; off >>= 1) {
            l0 += __shfl_xor(l0, off);
            l1 += __shfl_xor(l1, off);
        }
        if (lane == ff) { l0f = l0; l1f = l1; }
    }
    if (lane < 16) {
        int f = f0 + fg * 16 + lane;
        if (f < FL) {
            float a0 = l0f + b2[0];
            float a1 = l1f + b2[1];
            const float* np = nz + ((size_t)b * FL + f) * 2;
            float g0 = -logf(-logf(np[0] + 1e-9f) + 1e-9f);
            float g1 = -logf(-logf(np[1] + 1e-9f) + 1e-9f);
            a0 += g0; a1 += g1;
            z[(size_t)(tz * 2 + b) * FL + f] = 1.f / (1.f + expf(a0 - a1));
        }
    }
}

// ---------------- transpose fp32 [tb][d][l] -> bf16 [tb][l][d] ----------------
__global__ __launch_bounds__(256) void k_tr(const float* __restrict__ xt,
                                            ushort* __restrict__ xtb) {
    __shared__ float s[64][129];
    int tb = blockIdx.y;
    int l0 = blockIdx.x * 64;
    int t  = threadIdx.x;
    const float* gp = xt + (size_t)tb * DKN * LL;
    int d = t >> 1, c0 = (t & 1) * 32;
#pragma unroll
    for (int j4 = 0; j4 < 8; j4++) {
        float4 v = *(const float4*)&gp[(size_t)d * LL + l0 + c0 + j4 * 4];
        s[c0 + j4 * 4 + 0][d] = v.x;
        s[c0 + j4 * 4 + 1][d] = v.y;
        s[c0 + j4 * 4 + 2][d] = v.z;
        s[c0 + j4 * 4 + 3][d] = v.w;
    }
    __syncthreads();
    int l = t >> 2, dc0 = (t & 3) * 32;
    ushort* o = xtb + (size_t)tb * LL * DKN + (size_t)(l0 + l) * DKN + dc0;
#pragma unroll
    for (int c8 = 0; c8 < 4; c8++) {
        union { ushort us[8]; uint4 v; } pk;
#pragma unroll
        for (int u = 0; u < 8; u++) pk.us[u] = f2bf(s[l][dc0 + c8 * 8 + u]);
        *(uint4*)&o[c8 * 8] = pk.v;
    }
}

// ---------------- fused scores + masked softmax, single GEMM pass ----------------
// block: 512 thr (8 waves), 16 q-rows; wave w owns k-cols [w*512, w*512+512).
// exp'd scores stored packed-bf16 in LDS [16][4104]; no max subtraction (|s|<~4).
// MFMA operands SWAPPED (kf as A, qf as B) so each lane holds 4 consecutive
// k-cols of one q-row -> packed 8B LDS writes (bank-conflict-free with pad).
#define SCOLS 4104
__global__ __launch_bounds__(512) void k_scores_soft(const ushort* __restrict__ xtb,
                                                     const int* __restrict__ mask,
                                                     float* __restrict__ out) {
    extern __shared__ char smem[];
    ushort* sbuf = (ushort*)smem;                       // [16][SCOLS]
    float*  wsum = (float*)(smem + 16 * SCOLS * 2);     // [8][16]
    int b  = blockIdx.y;
    int l0 = blockIdx.x * 16;
    int t = threadIdx.x, w = t >> 6, lane = t & 63;
    int g = lane >> 4, c = lane & 15;
    const ushort* A = xtb + (size_t)b * LL * DKN;        // qf [l][d]
    const ushort* B = xtb + (size_t)(2 + b) * LL * DKN;  // kf [m][d]
    const int* mk = mask + (size_t)b * LL;
    const float sc = 0.08838834764831843f;  // 1/sqrt(128)
    bf16x8 af[4];
#pragma unroll
    for (int kk = 0; kk < 4; kk++)
        af[kk] = *(const bf16x8*)&A[(size_t)(l0 + c) * DKN + kk * 32 + g * 8];
    float rsum = 0.f;
    for (int mt = 0; mt < 8; mt++) {
        int m0 = w * 512 + mt * 64;
        f32x4 acc[4] = {};
#pragma unroll
        for (int kk = 0; kk < 4; kk++) {
            bf16x8 bfr[4];
#pragma unroll
            for (int nt = 0; nt < 4; nt++)
                bfr[nt] = *(const bf16x8*)&B[(size_t)(m0 + nt * 16 + c) * DKN + kk * 32 + g * 8];
#pragma unroll
            for (int nt = 0; nt < 4; nt++)
                acc[nt] = __builtin_amdgcn_mfma_f32_16x16x32_bf16(bfr[nt], af[kk], acc[nt], 0, 0, 0);
        }
        // lane holds D[row=m0+nt*16+g*4+r][col=l0+c]
#pragma unroll
        for (int nt = 0; nt < 4; nt++) {
            int mbase = m0 + nt * 16 + g * 4;
            int4 mv = *(const int4*)&mk[mbase];
            float e0 = mv.x ? __expf(acc[nt][0] * sc) : 0.f;
            float e1 = mv.y ? __expf(acc[nt][1] * sc) : 0.f;
            float e2 = mv.z ? __expf(acc[nt][2] * sc) : 0.f;
            float e3 = mv.w ? __expf(acc[nt][3] * sc) : 0.f;
            rsum += (e0 + e1) + (e2 + e3);
            uint2 pk;
            pk.x = (unsigned)f2bf(e0) | ((unsigned)f2bf(e1) << 16);
            pk.y = (unsigned)f2bf(e2) | ((unsigned)f2bf(e3) << 16);
            *(uint2*)&sbuf[(size_t)c * SCOLS + mbase] = pk;
        }
    }
    // reduce row sums across the 4 g-groups (lanes with same c)
    rsum += __shfl_xor(rsum, 16);
    rsum += __shfl_xor(rsum, 32);
    if (lane < 16) wsum[w * 16 + lane] = rsum;
    __syncthreads();
    // readback: wave w scales+writes cols [w*512, w*512+512) of all 16 rows
    float* ob = out + ((size_t)(b * LL + l0)) * LL;
    int col0 = w * 512 + lane * 8;
#pragma unroll 4
    for (int rr = 0; rr < 16; rr++) {
        float S = 0.f;
#pragma unroll
        for (int ww = 0; ww < 8; ww++) S += wsum[ww * 16 + rr];
        float* orow = ob + (size_t)rr * LL;
        uint4 v = *(const uint4*)&sbuf[(size_t)rr * SCOLS + col0];
        if (S > 0.f) {
            float inv = 1.0f / S;
            float4 r0, r1;
            r0.x = bfbits(v.x << 16) * inv;  r0.y = bfbits(v.x & 0xffff0000u) * inv;
            r0.z = bfbits(v.y << 16) * inv;  r0.w = bfbits(v.y & 0xffff0000u) * inv;
            r1.x = bfbits(v.z << 16) * inv;  r1.y = bfbits(v.z & 0xffff0000u) * inv;
            r1.z = bfbits(v.w << 16) * inv;  r1.w = bfbits(v.w & 0xffff0000u) * inv;
            *(float4*)&orow[col0] = r0;
            *(float4*)&orow[col0 + 4] = r1;
        } else {
            const float u = 2.44140625e-4f;  // 1/4096 (fully-masked row: uniform)
            float4 r = make_float4(u, u, u, u);
            *(float4*)&orow[col0] = r;
            *(float4*)&orow[col0 + 4] = r;
        }
    }
}

extern "C" void kernel_launch(void* const* d_in, const int* in_sizes, int n_in,
                              void* d_out, int out_size, void* d_ws, size_t ws_size,
                              hipStream_t stream) {
    (void)in_sizes; (void)n_in; (void)out_size; (void)ws_size;
    const float* query  = (const float*)d_in[0];
    const float* key    = (const float*)d_in[1];
    const int*   mask   = (const int*)d_in[2];
    const float* Wq     = (const float*)d_in[3];
    const float* bq     = (const float*)d_in[4];
    const float* Wk     = (const float*)d_in[5];
    const float* bk     = (const float*)d_in[6];
    const float* qW1    = (const float*)d_in[7];
    const float* qb1    = (const float*)d_in[8];
    const float* qW2    = (const float*)d_in[9];
    const float* qb2    = (const float*)d_in[10];
    const float* kW1    = (const float*)d_in[11];
    const float* kb1    = (const float*)d_in[12];
    const float* kW2    = (const float*)d_in[13];
    const float* kb2    = (const float*)d_in[14];
    const float* qnoise = (const float*)d_in[15];
    const float* knoise = (const float*)d_in[16];

    float*  ws   = (float*)d_ws;
    float2* tw   = (float2*)(ws + TW_OFF);
    float*  xt   = ws + XT_OFF;                 // [tensor][b][d][l] fp32
    float2* spec = (float2*)(ws + SPEC_OFF);    // [tensor*2+b][d][2049]
    ushort* xtb  = (ushort*)(ws + SPEC_OFF);    // bf16 [tb][l][d], aliases spec
    float*  zsel = ws + Z_OFF;
    ushort* qkh  = (ushort*)(ws + QKH_OFF);     // [q|k][2][4096][768] bf16
    ushort* wh   = (ushort*)(ws + WH_OFF);      // [Wq|Wk][128][768] bf16
    float*  out  = (float*)d_out;

    const int NQK = 2 * LL * DMOD;   // 6291456
    const int NW  = DKN * DMOD;      // 98304

    k_twiddle<<<dim3(8), dim3(256), 0, stream>>>(tw);
    k_cvt<<<dim3(NQK / 2048, 2), dim3(256), 0, stream>>>(query, key, qkh, NQK);
    k_cvt<<<dim3(NW / 2048, 2), dim3(256), 0, stream>>>(Wq, Wk, wh, NW);
    k_proj<<<dim3(64, 2, 2), dim3(256), 0, stream>>>(qkh, wh, bq, bk, xt);
    k_fft4<0><<<dim3(512), dim3(512), 0, stream>>>(xt, spec, nullptr, nullptr, tw);
    k_sel2<<<dim3(33, 2, 2), dim3(256), 0, stream>>>(spec, qW1, qb1, qW2, qb2,
                                                     kW1, kb1, kW2, kb2, qnoise, knoise, zsel);
    k_fft4<1><<<dim3(512), dim3(512), 0, stream>>>(nullptr, spec, zsel, xt, tw);
    k_tr<<<dim3(64, 4), dim3(256), 0, stream>>>(xt, xtb);
    size_t smem = 16 * SCOLS * 2 + 8 * 16 * 4;   // 131840 B
    k_scores_soft<<<dim3(256, 2), dim3(512), smem, stream>>>(xtb, mask, out);
}

// Round 8
// 347.722 us; speedup vs baseline: 1.1706x; 1.0280x over previous
//
#include <hip/hip_runtime.h>
#include <hip/hip_bf16.h>

#define LL 4096
#define FL 2049
#define DKN 128
#define DMOD 768

// ws layout (float units)
#define TW_OFF   0                          // 2048 float2
#define XT_OFF   4096                       // [2][2][128][4096] fp32 = 2097152 floats
#define SPEC_OFF (4096 + 2097152)           // [512][2049] float2 = 2098176 floats
#define Z_OFF    (SPEC_OFF + 2098176)       // [2][2][2049]
// xtb (bf16 [4][4096][128]) aliases the spec region (dead after irfft)
#define QKH_OFF  4207624                    // bf16 [q|k][2][4096][768] = 12582912 halves = 6291456 floats
#define WH_OFF   (QKH_OFF + 6291456)        // bf16 [Wq|Wk][128][768]

using bf16x8 = __attribute__((ext_vector_type(8))) short;
using f32x4  = __attribute__((ext_vector_type(4))) float;

__device__ __forceinline__ float2 cmul(float2 a, float2 b) {
    return make_float2(a.x * b.x - a.y * b.y, a.x * b.y + a.y * b.x);
}
__device__ __forceinline__ int SWZ(int a) { return a ^ ((a >> 4) & 15); }
__device__ __forceinline__ ushort f2bf(float f) {
    __hip_bfloat16 h = __float2bfloat16(f);
    return *(ushort*)&h;
}

// ---------------- twiddle table ----------------
__global__ void k_twiddle(float2* __restrict__ tw) {
    int j = blockIdx.x * 256 + threadIdx.x;
    if (j < 2048) {
        double a = -2.0 * 3.14159265358979323846 * (double)j / 4096.0;
        tw[j] = make_float2((float)cos(a), (float)sin(a));
    }
}

// ---------------- fp32 -> bf16 (two sources per launch) ----------------
__global__ __launch_bounds__(256) void k_cvt(const float* __restrict__ s0,
                                             const float* __restrict__ s1,
                                             ushort* __restrict__ hi, int n) {
    const float* src = blockIdx.y ? s1 : s0;
    ushort* h = hi + (size_t)blockIdx.y * n;
    int i8 = (blockIdx.x * 256 + threadIdx.x) * 8;
    if (i8 >= n) return;
    float4 a = *(const float4*)&src[i8];
    float4 b = *(const float4*)&src[i8 + 4];
    float v[8] = {a.x, a.y, a.z, a.w, b.x, b.y, b.z, b.w};
    union { ushort us[8]; uint4 q; } ph;
#pragma unroll
    for (int u = 0; u < 8; u++) ph.us[u] = f2bf(v[u]);
    *(uint4*)&h[i8] = ph.q;
}

// ---------------- projection GEMM (bf16 MFMA): xt[tz*2+b][d][l] = X . W^T + bias ----------------
__global__ __launch_bounds__(256) void k_proj(const ushort* __restrict__ XH,
                                              const ushort* __restrict__ WH,
                                              const float* __restrict__ bq,
                                              const float* __restrict__ bk,
                                              float* __restrict__ xt) {
    int tz = blockIdx.z, b = blockIdx.y;
    int l0 = blockIdx.x * 64;
    int t = threadIdx.x, w = t >> 6, lane = t & 63;
    int g = lane >> 4, c = lane & 15;
    size_t xrow0 = ((size_t)(tz * 2 + b)) * LL + l0;
    const ushort* WHt = WH + (size_t)tz * DKN * DMOD;
    const float* bias = tz ? bk : bq;
    float* outp = xt + (size_t)(tz * 2 + b) * DKN * LL;
    f32x4 acc[2][4] = {};
    for (int ks = 0; ks < 24; ks++) {
        int kb = ks * 32 + g * 8;
        bf16x8 ah[2], xh[4];
#pragma unroll
        for (int dt = 0; dt < 2; dt++)
            ah[dt] = *(const bf16x8*)&WHt[(size_t)(w * 32 + dt * 16 + c) * DMOD + kb];
#pragma unroll
        for (int nt = 0; nt < 4; nt++)
            xh[nt] = *(const bf16x8*)&XH[(xrow0 + nt * 16 + c) * DMOD + kb];
#pragma unroll
        for (int dt = 0; dt < 2; dt++)
#pragma unroll
            for (int nt = 0; nt < 4; nt++)
                acc[dt][nt] = __builtin_amdgcn_mfma_f32_16x16x32_bf16(ah[dt], xh[nt], acc[dt][nt], 0, 0, 0);
    }
#pragma unroll
    for (int dt = 0; dt < 2; dt++)
#pragma unroll
        for (int r = 0; r < 4; r++) {
            int d = w * 32 + dt * 16 + g * 4 + r;
            float bd = bias[d];
#pragma unroll
            for (int nt = 0; nt < 4; nt++)
                outp[(size_t)d * LL + l0 + nt * 16 + c] = acc[dt][nt][r] + bd;
        }
}

// ---------------- radix-4 in-place Stockham FFT (N=4096), swizzled LDS, LDS twiddles ----------------
template <int INV>
__global__ __launch_bounds__(512) void k_fft4(const float* __restrict__ xin,
                                              float2* __restrict__ spec,
                                              const float* __restrict__ zsel,
                                              float* __restrict__ xout,
                                              const float2* __restrict__ tw) {
    __shared__ float2 buf[4096];
    __shared__ float2 ltw[2048];
    int ser = blockIdx.x;   // (tensor*2+b)*128 + d
    int t   = threadIdx.x;
    for (int i = t; i < 2048; i += 512) ltw[i] = tw[i];
    if (!INV) {
        const float* x = xin + (size_t)ser * LL;
        for (int i = t; i < 4096; i += 512) buf[SWZ(i)] = make_float2(x[i], 0.f);
    } else {
        const float2* sp = spec + (size_t)ser * FL;
        const float*  zz = zsel + (size_t)(ser >> 7) * FL;
        for (int f = t; f < FL; f += 512) {
            float2 v = sp[f];
            float  m = zz[f];
            float2 vm = make_float2(v.x * m, v.y * m);
            buf[SWZ(f)] = vm;
            if (f > 0 && f < 2048) buf[SWZ(4096 - f)] = make_float2(vm.x, -vm.y);
        }
    }
    __syncthreads();
#pragma unroll
    for (int st = 0; st < 6; st++) {
        int Lm1 = (1 << (2 * st)) - 1;
        float2 x0[2], x1[2], x2[2], x3[2];
#pragma unroll
        for (int ii = 0; ii < 2; ii++) {
            int idx = t + 512 * ii;
            x0[ii] = buf[SWZ(idx)];
            x1[ii] = buf[SWZ(idx + 1024)];
            x2[ii] = buf[SWZ(idx + 2048)];
            x3[ii] = buf[SWZ(idx + 3072)];
        }
        __syncthreads();
#pragma unroll
        for (int ii = 0; ii < 2; ii++) {
            int idx = t + 512 * ii;
            int q = idx & Lm1;
            int r = idx - q;
            int wbase = q + (r << 2);
            int L = Lm1 + 1;
            float2 a0 = x0[ii], a1 = x1[ii], a2 = x2[ii], a3 = x3[ii];
            float2 t0 = make_float2(a0.x + a2.x, a0.y + a2.y);
            float2 t1 = make_float2(a0.x - a2.x, a0.y - a2.y);
            float2 t2 = make_float2(a1.x + a3.x, a1.y + a3.y);
            float2 t3 = make_float2(a1.x - a3.x, a1.y - a3.y);
            float2 y0 = make_float2(t0.x + t2.x, t0.y + t2.y);
            float2 y2 = make_float2(t0.x - t2.x, t0.y - t2.y);
            float2 y1, y3;
            if (!INV) {
                y1 = make_float2(t1.x + t3.y, t1.y - t3.x);
                y3 = make_float2(t1.x - t3.y, t1.y + t3.x);
            } else {
                y1 = make_float2(t1.x - t3.y, t1.y + t3.x);
                y3 = make_float2(t1.x + t3.y, t1.y - t3.x);
            }
            float2 w1 = ltw[r];
            float2 w2 = ltw[2 * r];
            if (INV) { w1.y = -w1.y; w2.y = -w2.y; }
            float2 w3 = cmul(w1, w2);
            buf[SWZ(wbase)]         = y0;
            buf[SWZ(wbase + L)]     = cmul(y1, w1);
            buf[SWZ(wbase + 2 * L)] = cmul(y2, w2);
            buf[SWZ(wbase + 3 * L)] = cmul(y3, w3);
        }
        __syncthreads();
    }
    if (!INV) {
        float2* sp = spec + (size_t)ser * FL;
        for (int f = t; f < FL; f += 512) sp[f] = buf[SWZ(f)];
    } else {
        float* xo = xout + (size_t)ser * LL;
        const float sc = 1.0f / 4096.0f;
        for (int i = t; i < 4096; i += 512) xo[i] = buf[SWZ(i)].x * sc;
    }
}

// ---------------- selector MLP, tiled: 64 freqs/block, 4 waves x 16 f, lane = hidden j ----------------
__global__ __launch_bounds__(256) void k_sel2(const float2* __restrict__ spec,
                                              const float* __restrict__ qW1,
                                              const float* __restrict__ qb1,
                                              const float* __restrict__ qW2,
                                              const float* __restrict__ qb2,
                                              const float* __restrict__ kW1,
                                              const float* __restrict__ kb1,
                                              const float* __restrict__ kW2,
                                              const float* __restrict__ kb2,
                                              const float* __restrict__ qnoise,
                                              const float* __restrict__ knoise,
                                              float* __restrict__ z) {
    int tz = blockIdx.z, b = blockIdx.y;
    int f0 = blockIdx.x * 64;
    const float* W1 = tz ? kW1 : qW1;
    const float* b1 = tz ? kb1 : qb1;
    const float* W2 = tz ? kW2 : qW2;
    const float* b2 = tz ? kb2 : qb2;
    const float* nz = tz ? knoise : qnoise;
    __shared__ float xr[64][132];
    const float2* sp = spec + (size_t)(tz * 2 + b) * DKN * FL;
    int t = threadIdx.x;
    {
        int d = t >> 1, half = t & 1;
        const float2* row = sp + (size_t)d * FL;
#pragma unroll
        for (int i2 = 0; i2 < 32; i2++) {
            int fi = f0 + half * 32 + i2;
            float v = (fi < FL) ? row[fi].x : 0.f;
            xr[half * 32 + i2][d] = v;
        }
    }
    __syncthreads();
    int lane = t & 63, fg = t >> 6;
    float acc[16];
    float bj = b1[lane];
#pragma unroll
    for (int ff = 0; ff < 16; ff++) acc[ff] = bj;
    const float4* w1r = (const float4*)&W1[(size_t)lane * 128];
    for (int d4 = 0; d4 < 32; d4++) {
        float4 wv = w1r[d4];
#pragma unroll
        for (int ff = 0; ff < 16; ff++) {
            float4 xv = *(const float4*)&xr[fg * 16 + ff][d4 * 4];
            acc[ff] = fmaf(xv.x, wv.x, acc[ff]);
            acc[ff] = fmaf(xv.y, wv.y, acc[ff]);
            acc[ff] = fmaf(xv.z, wv.z, acc[ff]);
            acc[ff] = fmaf(xv.w, wv.w, acc[ff]);
        }
    }
    float w2a = W2[lane], w2b = W2[64 + lane];
    float l0f = 0.f, l1f = 0.f;
#pragma unroll
    for (int ff = 0; ff < 16; ff++) {
        float h = fmaxf(acc[ff], 0.f);
        float l0 = h * w2a, l1 = h * w2b;
#pragma unroll
        for (int off = 32; off >= 1; off >>= 1) {
            l0 += __shfl_xor(l0, off);
            l1 += __shfl_xor(l1, off);
        }
        if (lane == ff) { l0f = l0; l1f = l1; }
    }
    if (lane < 16) {
        int f = f0 + fg * 16 + lane;
        if (f < FL) {
            float a0 = l0f + b2[0];
            float a1 = l1f + b2[1];
            const float* np = nz + ((size_t)b * FL + f) * 2;
            float g0 = -logf(-logf(np[0] + 1e-9f) + 1e-9f);
            float g1 = -logf(-logf(np[1] + 1e-9f) + 1e-9f);
            a0 += g0; a1 += g1;
            z[(size_t)(tz * 2 + b) * FL + f] = 1.f / (1.f + expf(a0 - a1));
        }
    }
}

// ---------------- transpose fp32 [tb][d][l] -> bf16 [tb][l][d] ----------------
__global__ __launch_bounds__(256) void k_tr(const float* __restrict__ xt,
                                            ushort* __restrict__ xtb) {
    __shared__ float s[64][129];
    int tb = blockIdx.y;
    int l0 = blockIdx.x * 64;
    int t  = threadIdx.x;
    const float* gp = xt + (size_t)tb * DKN * LL;
    int d = t >> 1, c0 = (t & 1) * 32;
#pragma unroll
    for (int j4 = 0; j4 < 8; j4++) {
        float4 v = *(const float4*)&gp[(size_t)d * LL + l0 + c0 + j4 * 4];
        s[c0 + j4 * 4 + 0][d] = v.x;
        s[c0 + j4 * 4 + 1][d] = v.y;
        s[c0 + j4 * 4 + 2][d] = v.z;
        s[c0 + j4 * 4 + 3][d] = v.w;
    }
    __syncthreads();
    int l = t >> 2, dc0 = (t & 3) * 32;
    ushort* o = xtb + (size_t)tb * LL * DKN + (size_t)(l0 + l) * DKN + dc0;
#pragma unroll
    for (int c8 = 0; c8 < 4; c8++) {
        union { ushort us[8]; uint4 v; } pk;
#pragma unroll
        for (int u = 0; u < 8; u++) pk.us[u] = f2bf(s[l][dc0 + c8 * 8 + u]);
        *(uint4*)&o[c8 * 8] = pk.v;
    }
}

// ---------------- fused scores + masked softmax, register-resident ----------------
// block: 1024 thr (16 waves), 16 q-rows; wave w owns k-cols [w*256, w*256+256).
// exp'd scores kept in 64 fp32 VGPRs per lane (statically indexed); LDS only
// for the 16x16 per-wave row sums. No max subtraction (|s| <~ 4, exp safe).
// MFMA operands swapped (kf as A, qf as B): lane g,c holds rows m0+nt*16+g*4+r,
// col l0+c -> 4 consecutive k-cols per acc reg -> float4 stores; the 4 g-groups
// jointly cover a full 64B line.
__global__ __launch_bounds__(1024, 4) void k_scores_soft(const ushort* __restrict__ xtb,
                                                         const int* __restrict__ mask,
                                                         float* __restrict__ out) {
    __shared__ float wsum[16][16];
    int b  = blockIdx.y;
    int l0 = blockIdx.x * 16;
    int t = threadIdx.x, w = t >> 6, lane = t & 63;
    int g = lane >> 4, c = lane & 15;
    const ushort* A = xtb + (size_t)b * LL * DKN;        // qf [l][d]
    const ushort* B = xtb + (size_t)(2 + b) * LL * DKN;  // kf [m][d]
    const int* mk = mask + (size_t)b * LL;
    const float sc = 0.08838834764831843f;  // 1/sqrt(128)
    bf16x8 af[4];
#pragma unroll
    for (int kk = 0; kk < 4; kk++)
        af[kk] = *(const bf16x8*)&A[(size_t)(l0 + c) * DKN + kk * 32 + g * 8];
    float ev[4][4][4];   // [mt][nt][r] — static indexing only
    float rsum = 0.f;
#pragma unroll
    for (int mt = 0; mt < 4; mt++) {
        int m0 = w * 256 + mt * 64;
        f32x4 acc[4] = {};
#pragma unroll
        for (int kk = 0; kk < 4; kk++) {
            bf16x8 bfr[4];
#pragma unroll
            for (int nt = 0; nt < 4; nt++)
                bfr[nt] = *(const bf16x8*)&B[(size_t)(m0 + nt * 16 + c) * DKN + kk * 32 + g * 8];
#pragma unroll
            for (int nt = 0; nt < 4; nt++)
                acc[nt] = __builtin_amdgcn_mfma_f32_16x16x32_bf16(bfr[nt], af[kk], acc[nt], 0, 0, 0);
        }
#pragma unroll
        for (int nt = 0; nt < 4; nt++) {
            int mbase = m0 + nt * 16 + g * 4;
            int4 mv = *(const int4*)&mk[mbase];
            float e0 = mv.x ? __expf(acc[nt][0] * sc) : 0.f;
            float e1 = mv.y ? __expf(acc[nt][1] * sc) : 0.f;
            float e2 = mv.z ? __expf(acc[nt][2] * sc) : 0.f;
            float e3 = mv.w ? __expf(acc[nt][3] * sc) : 0.f;
            ev[mt][nt][0] = e0; ev[mt][nt][1] = e1;
            ev[mt][nt][2] = e2; ev[mt][nt][3] = e3;
            rsum += (e0 + e1) + (e2 + e3);
        }
    }
    // reduce row sum across the 4 g-groups (lanes sharing c)
    rsum += __shfl_xor(rsum, 16);
    rsum += __shfl_xor(rsum, 32);
    if (lane < 16) wsum[w][lane] = rsum;
    __syncthreads();
    float S = 0.f;
#pragma unroll
    for (int ww = 0; ww < 16; ww++) S += wsum[ww][c];   // broadcast reads
    bool ok = (S > 0.f);
    float inv = ok ? 1.0f / S : 0.f;
    const float u = 2.44140625e-4f;   // 1/4096 (fully-masked row: uniform)
    float* orow = out + ((size_t)(b * LL + l0 + c)) * LL;
#pragma unroll
    for (int mt = 0; mt < 4; mt++)
#pragma unroll
        for (int nt = 0; nt < 4; nt++) {
            int mbase = w * 256 + mt * 64 + nt * 16 + g * 4;
            float4 r;
            r.x = ok ? ev[mt][nt][0] * inv : u;
            r.y = ok ? ev[mt][nt][1] * inv : u;
            r.z = ok ? ev[mt][nt][2] * inv : u;
            r.w = ok ? ev[mt][nt][3] * inv : u;
            *(float4*)&orow[mbase] = r;
        }
}

extern "C" void kernel_launch(void* const* d_in, const int* in_sizes, int n_in,
                              void* d_out, int out_size, void* d_ws, size_t ws_size,
                              hipStream_t stream) {
    (void)in_sizes; (void)n_in; (void)out_size; (void)ws_size;
    const float* query  = (const float*)d_in[0];
    const float* key    = (const float*)d_in[1];
    const int*   mask   = (const int*)d_in[2];
    const float* Wq     = (const float*)d_in[3];
    const float* bq     = (const float*)d_in[4];
    const float* Wk     = (const float*)d_in[5];
    const float* bk     = (const float*)d_in[6];
    const float* qW1    = (const float*)d_in[7];
    const float* qb1    = (const float*)d_in[8];
    const float* qW2    = (const float*)d_in[9];
    const float* qb2    = (const float*)d_in[10];
    const float* kW1    = (const float*)d_in[11];
    const float* kb1    = (const float*)d_in[12];
    const float* kW2    = (const float*)d_in[13];
    const float* kb2    = (const float*)d_in[14];
    const float* qnoise = (const float*)d_in[15];
    const float* knoise = (const float*)d_in[16];

    float*  ws   = (float*)d_ws;
    float2* tw   = (float2*)(ws + TW_OFF);
    float*  xt   = ws + XT_OFF;                 // [tensor][b][d][l] fp32
    float2* spec = (float2*)(ws + SPEC_OFF);    // [tensor*2+b][d][2049]
    ushort* xtb  = (ushort*)(ws + SPEC_OFF);    // bf16 [tb][l][d], aliases spec
    float*  zsel = ws + Z_OFF;
    ushort* qkh  = (ushort*)(ws + QKH_OFF);     // [q|k][2][4096][768] bf16
    ushort* wh   = (ushort*)(ws + WH_OFF);      // [Wq|Wk][128][768] bf16
    float*  out  = (float*)d_out;

    const int NQK = 2 * LL * DMOD;   // 6291456
    const int NW  = DKN * DMOD;      // 98304

    k_twiddle<<<dim3(8), dim3(256), 0, stream>>>(tw);
    k_cvt<<<dim3(NQK / 2048, 2), dim3(256), 0, stream>>>(query, key, qkh, NQK);
    k_cvt<<<dim3(NW / 2048, 2), dim3(256), 0, stream>>>(Wq, Wk, wh, NW);
    k_proj<<<dim3(64, 2, 2), dim3(256), 0, stream>>>(qkh, wh, bq, bk, xt);
    k_fft4<0><<<dim3(512), dim3(512), 0, stream>>>(xt, spec, nullptr, nullptr, tw);
    k_sel2<<<dim3(33, 2, 2), dim3(256), 0, stream>>>(spec, qW1, qb1, qW2, qb2,
                                                     kW1, kb1, kW2, kb2, qnoise, knoise, zsel);
    k_fft4<1><<<dim3(512), dim3(512), 0, stream>>>(nullptr, spec, zsel, xt, tw);
    k_tr<<<dim3(64, 4), dim3(256), 0, stream>>>(xt, xtb);
    k_scores_soft<<<dim3(256, 2), dim3(1024), 0, stream>>>(xtb, mask, out);
}